// Round 1
// baseline (4161.642 us; speedup 1.0000x reference)
//
#include <hip/hip_runtime.h>
#include <math.h>

#define RDIM 512
#define CDIM 512
#define EDIM 256
#define HDIM 8
#define DDIM 32

// ---------------------------------------------------------------------------
// Kernel 1: fused QKV projection.
// Block handles 16 rows of x ([16,256]) and all 256 output columns for Q,K,V.
// x tile staged in LDS k-major (xT[kk][rr]) so inner loop reads are uniform
// (broadcast) float4s. W column loads coalesced across threads.
// q gets * scaling * (1-mask).
// ---------------------------------------------------------------------------
__global__ __launch_bounds__(256) void qkv_proj_kernel(
    const float* __restrict__ x, const float* __restrict__ mask,
    const float* __restrict__ Wq, const float* __restrict__ bq,
    const float* __restrict__ Wk, const float* __restrict__ bk,
    const float* __restrict__ Wv, const float* __restrict__ bv,
    float* __restrict__ q, float* __restrict__ k, float* __restrict__ v)
{
    __shared__ float xT[EDIM][20];   // k-major, padded to 20 for b128-aligned rows
    const int t = threadIdx.x;
    const int row0 = blockIdx.x * 16;

    #pragma unroll
    for (int rr = 0; rr < 16; ++rr) {
        xT[t][rr] = x[(size_t)(row0 + rr) * EDIM + t];
    }
    __syncthreads();

    float accQ[16], accK[16], accV[16];
    #pragma unroll
    for (int i = 0; i < 16; ++i) { accQ[i] = 0.f; accK[i] = 0.f; accV[i] = 0.f; }

    for (int kk = 0; kk < EDIM; ++kk) {
        const float wq = Wq[kk * EDIM + t];
        const float wk = Wk[kk * EDIM + t];
        const float wv = Wv[kk * EDIM + t];
        const float4* xr = (const float4*)(&xT[kk][0]);
        #pragma unroll
        for (int c = 0; c < 4; ++c) {
            float4 xv = xr[c];
            accQ[4*c+0] += xv.x * wq; accK[4*c+0] += xv.x * wk; accV[4*c+0] += xv.x * wv;
            accQ[4*c+1] += xv.y * wq; accK[4*c+1] += xv.y * wk; accV[4*c+1] += xv.y * wv;
            accQ[4*c+2] += xv.z * wq; accK[4*c+2] += xv.z * wk; accV[4*c+2] += xv.z * wv;
            accQ[4*c+3] += xv.w * wq; accK[4*c+3] += xv.w * wk; accV[4*c+3] += xv.w * wv;
        }
    }

    const float scaling = 0.0078125f;   // D^-0.5 / sqrt(R) = 1/128 exactly
    const float bqv = bq[t], bkv = bk[t], bvv = bv[t];
    #pragma unroll
    for (int rr = 0; rr < 16; ++rr) {
        const size_t row = row0 + rr;
        const float m = mask[row];
        q[row * EDIM + t] = (accQ[rr] + bqv) * scaling * (1.0f - m);
        k[row * EDIM + t] = accK[rr] + bkv;
        v[row * EDIM + t] = accV[rr] + bvv;
    }
}

// ---------------------------------------------------------------------------
// Kernel 2: attention logits.  logits[h,i,j] = sum_{r,d} q[r,i,h,d]*k[r,j,h,d]
// Per-head GEMM with K = R*D = 16384.  Block = 64x64 tile of (i,j), loops over
// r staging [64,32] q/k sub-tiles into LDS d-major.  16x16 threads x 4x4 acc.
// Writes logits directly into d_out's probs region (softmax-ed in place later).
// ---------------------------------------------------------------------------
__global__ __launch_bounds__(256) void attn_logits_kernel(
    const float* __restrict__ q, const float* __restrict__ k,
    float* __restrict__ logits)
{
    __shared__ float As[DDIM][68];   // d-major: As[d][ii]
    __shared__ float Bs[DDIM][68];
    const int t = threadIdx.x;
    const int tx = t & 15, ty = t >> 4;
    const int j0 = blockIdx.x * 64;
    const int i0 = blockIdx.y * 64;
    const int h  = blockIdx.z;

    float acc[4][4];
    #pragma unroll
    for (int u = 0; u < 4; ++u)
        #pragma unroll
        for (int w = 0; w < 4; ++w) acc[u][w] = 0.f;

    for (int r = 0; r < RDIM; ++r) {
        const size_t base = (size_t)r * CDIM * EDIM + h * DDIM;
        #pragma unroll
        for (int c = 0; c < 2; ++c) {
            const int f  = t + 256 * c;         // 0..511 float4 slots
            const int ii = f >> 3;              // 0..63
            const int d4 = (f & 7) * 4;         // 0..28
            float4 av = *(const float4*)(q + base + (size_t)(i0 + ii) * EDIM + d4);
            float4 bv = *(const float4*)(k + base + (size_t)(j0 + ii) * EDIM + d4);
            As[d4+0][ii] = av.x; As[d4+1][ii] = av.y; As[d4+2][ii] = av.z; As[d4+3][ii] = av.w;
            Bs[d4+0][ii] = bv.x; Bs[d4+1][ii] = bv.y; Bs[d4+2][ii] = bv.z; Bs[d4+3][ii] = bv.w;
        }
        __syncthreads();
        #pragma unroll
        for (int kk = 0; kk < DDIM; ++kk) {
            float4 a = *(const float4*)(&As[kk][ty * 4]);
            float4 b = *(const float4*)(&Bs[kk][tx * 4]);
            acc[0][0] += a.x*b.x; acc[0][1] += a.x*b.y; acc[0][2] += a.x*b.z; acc[0][3] += a.x*b.w;
            acc[1][0] += a.y*b.x; acc[1][1] += a.y*b.y; acc[1][2] += a.y*b.z; acc[1][3] += a.y*b.w;
            acc[2][0] += a.z*b.x; acc[2][1] += a.z*b.y; acc[2][2] += a.z*b.z; acc[2][3] += a.z*b.w;
            acc[3][0] += a.w*b.x; acc[3][1] += a.w*b.y; acc[3][2] += a.w*b.z; acc[3][3] += a.w*b.w;
        }
        __syncthreads();
    }

    #pragma unroll
    for (int u = 0; u < 4; ++u) {
        const int i = i0 + ty * 4 + u;
        float4 val = make_float4(acc[u][0], acc[u][1], acc[u][2], acc[u][3]);
        *(float4*)(logits + (size_t)h * CDIM * CDIM + (size_t)i * CDIM + j0 + tx * 4) = val;
    }
}

// ---------------------------------------------------------------------------
// Kernel 3: mask (over the i axis, per mask[0][i]) + softmax over j, in place.
// One block per (h,i) row of 512.
// ---------------------------------------------------------------------------
__global__ __launch_bounds__(256) void softmax_kernel(
    float* __restrict__ probs, const float* __restrict__ mask)
{
    const int hi = blockIdx.x;            // h*512 + i
    const int i = hi & (CDIM - 1);
    const float mi = mask[i];             // mask[0][i]
    float* row = probs + (size_t)hi * CDIM;
    const int t = threadIdx.x;

    float v0 = row[t], v1 = row[t + 256];
    const float keep = 1.0f - mi;
    v0 = v0 * keep + mi * (-10000.0f);
    v1 = v1 * keep + mi * (-10000.0f);

    float m = fmaxf(v0, v1);
    #pragma unroll
    for (int off = 32; off > 0; off >>= 1) m = fmaxf(m, __shfl_xor(m, off));
    __shared__ float red[4];
    if ((t & 63) == 0) red[t >> 6] = m;
    __syncthreads();
    m = fmaxf(fmaxf(red[0], red[1]), fmaxf(red[2], red[3]));

    const float e0 = expf(v0 - m), e1 = expf(v1 - m);
    float s = e0 + e1;
    #pragma unroll
    for (int off = 32; off > 0; off >>= 1) s += __shfl_xor(s, off);
    __syncthreads();
    if ((t & 63) == 0) red[t >> 6] = s;
    __syncthreads();
    s = red[0] + red[1] + red[2] + red[3];

    const float inv = 1.0f / s;
    row[t] = e0 * inv;
    row[t + 256] = e1 * inv;
}

// ---------------------------------------------------------------------------
// Kernel 4: context[r,i,h,d] = sum_j probs[h,i,j] * v[r,j,h,d]
// Block = (r, h, 64-wide i tile); loops over j in 64-tiles staged in LDS.
// Thread owns 2 i-rows x 4 d-cols.
// ---------------------------------------------------------------------------
__global__ __launch_bounds__(256) void context_kernel(
    const float* __restrict__ probs, const float* __restrict__ v,
    float* __restrict__ ctx)
{
    __shared__ float Ps[64][65];
    __shared__ float Vs[64][DDIM];
    const int t = threadIdx.x;
    const int i0 = blockIdx.x * 64;   // 8 tiles
    const int h  = blockIdx.y;        // 8
    const int r  = blockIdx.z;        // 512
    const int dq = t & 7, iw = t >> 3;
    const int d0 = dq * 4;

    float a0x = 0.f, a0y = 0.f, a0z = 0.f, a0w = 0.f;
    float a1x = 0.f, a1y = 0.f, a1z = 0.f, a1w = 0.f;

    for (int j0 = 0; j0 < CDIM; j0 += 64) {
        #pragma unroll
        for (int c = 0; c < 4; ++c) {
            const int f  = t + 256 * c;         // 0..1023
            const int ii = f >> 4;              // 0..63
            const int j4 = (f & 15) * 4;        // 0..60
            float4 pv = *(const float4*)(probs + (size_t)h * CDIM * CDIM
                                         + (size_t)(i0 + ii) * CDIM + j0 + j4);
            Ps[ii][j4+0] = pv.x; Ps[ii][j4+1] = pv.y; Ps[ii][j4+2] = pv.z; Ps[ii][j4+3] = pv.w;
        }
        #pragma unroll
        for (int c = 0; c < 2; ++c) {
            const int f  = t + 256 * c;         // 0..511
            const int jj = f >> 3;              // 0..63
            const int d4 = (f & 7) * 4;
            *(float4*)(&Vs[jj][d4]) = *(const float4*)(v + (size_t)r * CDIM * EDIM
                                        + (size_t)(j0 + jj) * EDIM + h * DDIM + d4);
        }
        __syncthreads();
        #pragma unroll 8
        for (int jj = 0; jj < 64; ++jj) {
            const float p0 = Ps[iw*2  ][jj];
            const float p1 = Ps[iw*2+1][jj];
            float4 vv = *(const float4*)(&Vs[jj][d0]);
            a0x += p0 * vv.x; a0y += p0 * vv.y; a0z += p0 * vv.z; a0w += p0 * vv.w;
            a1x += p1 * vv.x; a1y += p1 * vv.y; a1z += p1 * vv.z; a1w += p1 * vv.w;
        }
        __syncthreads();
    }

    const size_t obase = (size_t)r * CDIM * EDIM + (size_t)(i0 + iw * 2) * EDIM + h * DDIM + d0;
    *(float4*)(ctx + obase)        = make_float4(a0x, a0y, a0z, a0w);
    *(float4*)(ctx + obase + EDIM) = make_float4(a1x, a1y, a1z, a1w);
}

// ---------------------------------------------------------------------------
// Kernel 5: output = context @ Wo + bo  (same structure as kernel 1)
// ---------------------------------------------------------------------------
__global__ __launch_bounds__(256) void out_proj_kernel(
    const float* __restrict__ ctx, const float* __restrict__ Wo,
    const float* __restrict__ bo, float* __restrict__ out)
{
    __shared__ float xT[EDIM][20];
    const int t = threadIdx.x;
    const int row0 = blockIdx.x * 16;

    #pragma unroll
    for (int rr = 0; rr < 16; ++rr) {
        xT[t][rr] = ctx[(size_t)(row0 + rr) * EDIM + t];
    }
    __syncthreads();

    float acc[16];
    #pragma unroll
    for (int i = 0; i < 16; ++i) acc[i] = 0.f;

    for (int kk = 0; kk < EDIM; ++kk) {
        const float w = Wo[kk * EDIM + t];
        const float4* xr = (const float4*)(&xT[kk][0]);
        #pragma unroll
        for (int c = 0; c < 4; ++c) {
            float4 xv = xr[c];
            acc[4*c+0] += xv.x * w;
            acc[4*c+1] += xv.y * w;
            acc[4*c+2] += xv.z * w;
            acc[4*c+3] += xv.w * w;
        }
    }

    const float b = bo[t];
    #pragma unroll
    for (int rr = 0; rr < 16; ++rr) {
        out[(size_t)(row0 + rr) * EDIM + t] = acc[rr] + b;
    }
}

// ---------------------------------------------------------------------------
extern "C" void kernel_launch(void* const* d_in, const int* in_sizes, int n_in,
                              void* d_out, int out_size, void* d_ws, size_t ws_size,
                              hipStream_t stream)
{
    const float* x    = (const float*)d_in[0];
    const float* mask = (const float*)d_in[1];
    const float* Wq   = (const float*)d_in[2];
    const float* bq   = (const float*)d_in[3];
    const float* Wk   = (const float*)d_in[4];
    const float* bk   = (const float*)d_in[5];
    const float* Wv   = (const float*)d_in[6];
    const float* bv   = (const float*)d_in[7];
    const float* Wo   = (const float*)d_in[8];
    const float* bo   = (const float*)d_in[9];

    float* out   = (float*)d_out;                        // [R,C,E]
    float* probs = out + (size_t)RDIM * CDIM * EDIM;     // [H,C,C], logits then softmax in place

    const size_t n = (size_t)RDIM * CDIM * EDIM;         // 67,108,864 floats
    float* ws = (float*)d_ws;
    float* q  = ws;                                      // fp32 [R,C,H,D]
    float* k  = ws + n;
    float* v  = ws + 2 * n;
    float* ctx = ws;                                     // reuses q after logits done

    qkv_proj_kernel<<<RDIM * CDIM / 16, 256, 0, stream>>>(x, mask, Wq, bq, Wk, bk, Wv, bv, q, k, v);
    attn_logits_kernel<<<dim3(8, 8, 8), 256, 0, stream>>>(q, k, probs);
    softmax_kernel<<<HDIM * CDIM, 256, 0, stream>>>(probs, mask);
    context_kernel<<<dim3(8, 8, 512), 256, 0, stream>>>(probs, v, ctx);
    out_proj_kernel<<<RDIM * CDIM / 16, 256, 0, stream>>>(ctx, Wo, bo, out);
}

// Round 2
// 918.435 us; speedup vs baseline: 4.5312x; 4.5312x over previous
//
#include <hip/hip_runtime.h>
#include <math.h>

#define R_ 512
#define C_ 512
#define E_ 256
#define H_ 8
#define D_ 32
#define RC_ (R_*C_)   // 262144

typedef __attribute__((ext_vector_type(8))) short bf16x8;
typedef __attribute__((ext_vector_type(4))) float f32x4;

__device__ inline ushort f2bf(float f) {
    union { float f; unsigned u; } v; v.f = f;
    unsigned r = v.u + 0x7FFFu + ((v.u >> 16) & 1u);   // RNE
    return (ushort)(r >> 16);
}

// Stage a [128 rows][32 bf16] tile into LDS with row pitch 40 elems (80 B:
// 16B-aligned, spreads rows across all bank quads -> conflict-free b128 r/w).
__device__ inline void stage_tile(const ushort* __restrict__ src, int stride,
                                  ushort* __restrict__ lds, int t) {
    #pragma unroll
    for (int c = 0; c < 2; ++c) {
        int f = t + 256 * c;
        int row = f >> 2, ch = f & 3;
        uint4 val = *(const uint4*)(src + (size_t)row * stride + ch * 8);
        *(uint4*)(lds + row * 40 + ch * 8) = val;
    }
}

#define MFMA_PREAMBLE                                   \
    const int t = threadIdx.x;                          \
    const int wid = t >> 6, l = t & 63;                 \
    const int wm = wid >> 1, wn = wid & 1;              \
    const int l15 = l & 15, lhi = l >> 4;               \
    f32x4 acc[4][4];                                    \
    _Pragma("unroll")                                   \
    for (int a_ = 0; a_ < 4; ++a_)                      \
        _Pragma("unroll")                               \
        for (int b_ = 0; b_ < 4; ++b_)                  \
            acc[a_][b_] = (f32x4){0.f, 0.f, 0.f, 0.f};

#define MFMA_STEP(As, Bs)                                                        \
    {                                                                            \
        bf16x8 af_[4], bf_[4];                                                   \
        _Pragma("unroll")                                                        \
        for (int f_ = 0; f_ < 4; ++f_) {                                         \
            af_[f_] = *(const bf16x8*)((As) + (wm*64 + f_*16 + l15)*40 + lhi*8); \
            bf_[f_] = *(const bf16x8*)((Bs) + (wn*64 + f_*16 + l15)*40 + lhi*8); \
        }                                                                        \
        _Pragma("unroll")                                                        \
        for (int m_ = 0; m_ < 4; ++m_)                                           \
            _Pragma("unroll")                                                    \
            for (int n_ = 0; n_ < 4; ++n_)                                       \
                acc[m_][n_] = __builtin_amdgcn_mfma_f32_16x16x32_bf16(           \
                    af_[m_], bf_[n_], acc[m_][n_], 0, 0, 0);                     \
    }

// ---------------------------------------------------------------------------
// x (fp32) -> xb (bf16), elementwise
// ---------------------------------------------------------------------------
__global__ __launch_bounds__(256) void convert_x(
    const float* __restrict__ x, ushort* __restrict__ xb)
{
    size_t idx = ((size_t)blockIdx.x * 256 + threadIdx.x) * 8;
    float4 a = *(const float4*)(x + idx);
    float4 b = *(const float4*)(x + idx + 4);
    ushort o[8] = {f2bf(a.x), f2bf(a.y), f2bf(a.z), f2bf(a.w),
                   f2bf(b.x), f2bf(b.y), f2bf(b.z), f2bf(b.w)};
    *(uint4*)(xb + idx) = *(uint4*)o;
}

// ---------------------------------------------------------------------------
// Transpose+convert the 4 weight matrices to n-major bf16 (B-operand layout).
// WTqkv[(proj*256+n)*256+k] = W_proj[k][n];  WoT[n*256+k] = Wo[k][n]
// ---------------------------------------------------------------------------
__global__ __launch_bounds__(256) void convert_w(
    const float* __restrict__ Wq, const float* __restrict__ Wk,
    const float* __restrict__ Wv, const float* __restrict__ Wo,
    ushort* __restrict__ WTqkv, ushort* __restrict__ WoT)
{
    const int id = blockIdx.x;      // 0..1023
    const int matn = id >> 8;       // 0..3 = q,k,v,o
    const int n = id & 255;
    const int k = threadIdx.x;      // 0..255
    const float* W = (matn == 0) ? Wq : (matn == 1) ? Wk : (matn == 2) ? Wv : Wo;
    ushort v = f2bf(W[(size_t)k * E_ + n]);
    if (matn < 3) WTqkv[((size_t)matn * E_ + n) * E_ + k] = v;
    else          WoT[(size_t)n * E_ + k] = v;
}

// ---------------------------------------------------------------------------
// Fused QKV projection, MFMA.  grid(6, 2048): x = n-tile over [Wq|Wk|Wv]
// (768 cols / 128), y = m-tile over 262144 rows / 128.  n fastest-varying so
// the 6 blocks sharing an x-panel are dispatched together (L2/LLC reuse).
// q -> qb[h][r][c][d] * (1/128) * (1-mask);  k -> kb[h][r][c][d];
// v -> vb[h][r][d][c]  (transposed for the context kernel's B-operand).
// ---------------------------------------------------------------------------
__global__ __launch_bounds__(256) void qkv_mfma(
    const ushort* __restrict__ xb, const ushort* __restrict__ WT,
    const float* __restrict__ bq, const float* __restrict__ bk,
    const float* __restrict__ bv, const float* __restrict__ mask,
    ushort* __restrict__ qb, ushort* __restrict__ kb, ushort* __restrict__ vb)
{
    __shared__ ushort As[128*40], Bs[128*40];
    const int nt = blockIdx.x;              // 0..5
    const int rc0 = blockIdx.y * 128;
    MFMA_PREAMBLE;

    const ushort* Abase = xb + (size_t)rc0 * E_;
    const ushort* Bbase = WT + (size_t)nt * 128 * E_;

    for (int it = 0; it < 8; ++it) {
        stage_tile(Abase + it * 32, E_, As, t);
        stage_tile(Bbase + it * 32, E_, Bs, t);
        __syncthreads();
        MFMA_STEP(As, Bs);
        __syncthreads();
    }

    const int proj = nt >> 1;
    const float* bias = (proj == 0) ? bq : (proj == 1) ? bk : bv;
    #pragma unroll
    for (int fn = 0; fn < 4; ++fn) {
        const int ncol = nt * 128 + wn * 64 + fn * 16 + l15;
        const int e = ncol & 255, h = e >> 5, d = e & 31;
        const float bval = bias[e];
        #pragma unroll
        for (int fm = 0; fm < 4; ++fm) {
            #pragma unroll
            for (int rg = 0; rg < 4; ++rg) {
                const int rc = rc0 + wm * 64 + fm * 16 + lhi * 4 + rg;
                const int r = rc >> 9, c = rc & 511;
                float val = acc[fm][fn][rg] + bval;
                if (proj == 0) {
                    val *= 0.0078125f * (1.0f - mask[rc]);
                    qb[(((size_t)h * R_ + r) * C_ + c) * D_ + d] = f2bf(val);
                } else if (proj == 1) {
                    kb[(((size_t)h * R_ + r) * C_ + c) * D_ + d] = f2bf(val);
                } else {
                    vb[(((size_t)h * R_ + r) * D_ + d) * C_ + c] = f2bf(val);
                }
            }
        }
    }
}

// ---------------------------------------------------------------------------
// Attention logits, MFMA.  logits[h,i,j] = sum_{r,d} q[r,i,h,d]*k[r,j,h,d].
// K = R*D = 16384 split 4-way over blockIdx.z (partials summed in softmax).
// grid(4 j-tiles, 4 i-tiles, 8 heads * 4 ksplits) = 512 blocks.
// ---------------------------------------------------------------------------
__global__ __launch_bounds__(256) void logits_mfma(
    const ushort* __restrict__ qb, const ushort* __restrict__ kb,
    float* __restrict__ partial)
{
    __shared__ ushort As[128*40], Bs[128*40];
    const int j0 = blockIdx.x * 128;
    const int i0 = blockIdx.y * 128;
    const int h = blockIdx.z >> 2, ks = blockIdx.z & 3;
    MFMA_PREAMBLE;

    for (int it = 0; it < 128; ++it) {
        const int r = ks * 128 + it;
        stage_tile(qb + (((size_t)h * R_ + r) * C_ + i0) * D_, D_, As, t);
        stage_tile(kb + (((size_t)h * R_ + r) * C_ + j0) * D_, D_, Bs, t);
        __syncthreads();
        MFMA_STEP(As, Bs);
        __syncthreads();
    }

    float* dst = partial + ((size_t)ks * H_ + h) * C_ * C_;
    #pragma unroll
    for (int fm = 0; fm < 4; ++fm) {
        #pragma unroll
        for (int rg = 0; rg < 4; ++rg) {
            const int i = i0 + wm * 64 + fm * 16 + lhi * 4 + rg;
            #pragma unroll
            for (int fn = 0; fn < 4; ++fn) {
                const int j = j0 + wn * 64 + fn * 16 + l15;
                dst[(size_t)i * C_ + j] = acc[fm][fn][rg];
            }
        }
    }
}

// ---------------------------------------------------------------------------
// Sum 4 K-split partials + i-axis mask (mask[0][i]) + softmax over j.
// Writes fp32 probs (output) and bf16 copy for the context GEMM.
// ---------------------------------------------------------------------------
__global__ __launch_bounds__(256) void softmax_kernel(
    const float* __restrict__ partial, const float* __restrict__ mask,
    float* __restrict__ probs, ushort* __restrict__ Pb)
{
    const int hi = blockIdx.x;            // h*512 + i
    const int i = hi & 511;
    const int t = threadIdx.x;
    const size_t base = (size_t)hi * C_;
    const size_t stride = (size_t)H_ * C_ * C_;
    float v0 = 0.f, v1 = 0.f;
    #pragma unroll
    for (int ksp = 0; ksp < 4; ++ksp) {
        v0 += partial[ksp * stride + base + t];
        v1 += partial[ksp * stride + base + t + 256];
    }
    const float mi = mask[i];
    const float keep = 1.0f - mi;
    v0 = v0 * keep + mi * (-10000.0f);
    v1 = v1 * keep + mi * (-10000.0f);

    float m = fmaxf(v0, v1);
    #pragma unroll
    for (int off = 32; off > 0; off >>= 1) m = fmaxf(m, __shfl_xor(m, off));
    __shared__ float red[4];
    if ((t & 63) == 0) red[t >> 6] = m;
    __syncthreads();
    m = fmaxf(fmaxf(red[0], red[1]), fmaxf(red[2], red[3]));

    const float e0 = expf(v0 - m), e1 = expf(v1 - m);
    float s = e0 + e1;
    #pragma unroll
    for (int off = 32; off > 0; off >>= 1) s += __shfl_xor(s, off);
    __syncthreads();
    if ((t & 63) == 0) red[t >> 6] = s;
    __syncthreads();
    s = red[0] + red[1] + red[2] + red[3];

    const float inv = 1.0f / s;
    const float p0 = e0 * inv, p1 = e1 * inv;
    probs[base + t] = p0;
    probs[base + t + 256] = p1;
    Pb[base + t] = f2bf(p0);
    Pb[base + t + 256] = f2bf(p1);
}

// ---------------------------------------------------------------------------
// Context, MFMA.  Per head: ctx2[i, n=(r,d)] = sum_j P[i,j] * vb[h][n][j].
// grid(4 i-tiles, 128 n-tiles, 8 heads); i fastest so the 4 blocks sharing a
// vb panel dispatch together.  Output repacked to ctxb[rc][e] bf16.
// ---------------------------------------------------------------------------
__global__ __launch_bounds__(256) void context_mfma(
    const ushort* __restrict__ Pb, const ushort* __restrict__ vb,
    ushort* __restrict__ ctxb)
{
    __shared__ ushort As[128*40], Bs[128*40];
    const int i0 = blockIdx.x * 128;
    const int n0 = blockIdx.y * 128;
    const int h = blockIdx.z;
    MFMA_PREAMBLE;

    const ushort* Abase = Pb + ((size_t)h * C_ + i0) * C_;
    const ushort* Bbase = vb + ((size_t)h * R_ * D_ + n0) * C_;  // (h*16384+n)*512

    for (int it = 0; it < 16; ++it) {
        stage_tile(Abase + it * 32, C_, As, t);
        stage_tile(Bbase + it * 32, C_, Bs, t);
        __syncthreads();
        MFMA_STEP(As, Bs);
        __syncthreads();
    }

    #pragma unroll
    for (int fn = 0; fn < 4; ++fn) {
        const int n = n0 + wn * 64 + fn * 16 + l15;   // 0..16383
        const int rr = n >> 5, d = n & 31;
        #pragma unroll
        for (int fm = 0; fm < 4; ++fm) {
            #pragma unroll
            for (int rg = 0; rg < 4; ++rg) {
                const int i = i0 + wm * 64 + fm * 16 + lhi * 4 + rg;
                const size_t rc = (size_t)rr * C_ + i;
                ctxb[rc * E_ + h * D_ + d] = f2bf(acc[fm][fn][rg]);
            }
        }
    }
}

// ---------------------------------------------------------------------------
// Output projection, MFMA.  out = ctx @ Wo + bo (fp32 out).
// grid(2 n-tiles, 2048 m-tiles), n fastest for A-panel reuse.
// ---------------------------------------------------------------------------
__global__ __launch_bounds__(256) void out_proj_mfma(
    const ushort* __restrict__ ctxb, const ushort* __restrict__ WoT,
    const float* __restrict__ bo, float* __restrict__ out)
{
    __shared__ ushort As[128*40], Bs[128*40];
    const int n0 = blockIdx.x * 128;
    const int rc0 = blockIdx.y * 128;
    MFMA_PREAMBLE;

    const ushort* Abase = ctxb + (size_t)rc0 * E_;
    const ushort* Bbase = WoT + (size_t)n0 * E_;

    for (int it = 0; it < 8; ++it) {
        stage_tile(Abase + it * 32, E_, As, t);
        stage_tile(Bbase + it * 32, E_, Bs, t);
        __syncthreads();
        MFMA_STEP(As, Bs);
        __syncthreads();
    }

    #pragma unroll
    for (int fn = 0; fn < 4; ++fn) {
        const int ncol = n0 + wn * 64 + fn * 16 + l15;
        const float bval = bo[ncol];
        #pragma unroll
        for (int fm = 0; fm < 4; ++fm) {
            #pragma unroll
            for (int rg = 0; rg < 4; ++rg) {
                const int rc = rc0 + wm * 64 + fm * 16 + lhi * 4 + rg;
                out[(size_t)rc * E_ + ncol] = acc[fm][fn][rg] + bval;
            }
        }
    }
}

// ---------------------------------------------------------------------------
extern "C" void kernel_launch(void* const* d_in, const int* in_sizes, int n_in,
                              void* d_out, int out_size, void* d_ws, size_t ws_size,
                              hipStream_t stream)
{
    const float* x    = (const float*)d_in[0];
    const float* mask = (const float*)d_in[1];
    const float* Wq   = (const float*)d_in[2];
    const float* bq   = (const float*)d_in[3];
    const float* Wk   = (const float*)d_in[4];
    const float* bk   = (const float*)d_in[5];
    const float* Wv   = (const float*)d_in[6];
    const float* bv   = (const float*)d_in[7];
    const float* Wo   = (const float*)d_in[8];
    const float* bo   = (const float*)d_in[9];

    float* out   = (float*)d_out;                       // [R,C,E] fp32
    float* probs = out + (size_t)RC_ * E_;              // [H,C,C] fp32

    char* ws = (char*)d_ws;
    ushort* qb      = (ushort*)(ws);                    // 128 MB  [h][r][c][d]
    ushort* kb      = (ushort*)(ws + 134217728ull);     // 128 MB  [h][r][c][d]
    ushort* vb      = (ushort*)(ws + 268435456ull);     // 128 MB  [h][r][d][c]
    ushort* xb      = (ushort*)(ws + 402653184ull);     // 128 MB  [rc][e]
    ushort* ctxb    = (ushort*)(ws + 536870912ull);     // 128 MB  [rc][e]
    float*  partial = (float*)(ws + 671088640ull);      // 32 MB   [4][h][i][j]
    ushort* Pb      = (ushort*)(ws + 704643072ull);     // 4 MB    [h][i][j]
    ushort* WTqkv   = (ushort*)(ws + 708837376ull);     // 384 KB
    ushort* WoT     = (ushort*)(ws + 709230592ull);     // 128 KB

    convert_x<<<32768, 256, 0, stream>>>(x, xb);
    convert_w<<<1024, 256, 0, stream>>>(Wq, Wk, Wv, Wo, WTqkv, WoT);
    qkv_mfma<<<dim3(6, 2048), 256, 0, stream>>>(xb, WTqkv, bq, bk, bv, mask, qb, kb, vb);
    logits_mfma<<<dim3(4, 4, 32), 256, 0, stream>>>(qb, kb, partial);
    softmax_kernel<<<4096, 256, 0, stream>>>(partial, mask, probs, Pb);
    context_mfma<<<dim3(4, 128, 8), 256, 0, stream>>>(Pb, vb, ctxb);
    out_proj_mfma<<<dim3(2, 2048), 256, 0, stream>>>(ctxb, WoT, bo, out);
}

// Round 3
// 714.263 us; speedup vs baseline: 5.8265x; 1.2858x over previous
//
#include <hip/hip_runtime.h>
#include <math.h>

#define R_ 512
#define C_ 512
#define E_ 256
#define H_ 8
#define D_ 32
#define RC_ (R_*C_)   // 262144
#define RP 136        // repack pitch (ushorts); mult of 8, breaks power-of-2 banks

typedef __attribute__((ext_vector_type(8))) short bf16x8;
typedef __attribute__((ext_vector_type(4))) float f32x4;

__device__ __forceinline__ ushort f2bf(float f) {
    union { float f; unsigned u; } v; v.f = f;
    unsigned r = v.u + 0x7FFFu + ((v.u >> 16) & 1u);   // RNE
    return (ushort)(r >> 16);
}
__device__ __forceinline__ float bf2f(ushort u) {
    union { unsigned u; float f; } v; v.u = ((unsigned)u) << 16;
    return v.f;
}

// 16B global->LDS direct copy (lane-linear dest), fallback = reg staging.
__device__ __forceinline__ void gll16(const ushort* g, ushort* l) {
#if __has_builtin(__builtin_amdgcn_global_load_lds)
    __builtin_amdgcn_global_load_lds(
        (const __attribute__((address_space(1))) unsigned*)(unsigned long long)g,
        (__attribute__((address_space(3))) unsigned*)(unsigned)(unsigned long long)l,
        16, 0, 0);
#else
    *(uint4*)l = *(const uint4*)g;
#endif
}

// 128x128 tile, 4 waves (2x2), 16x16x32 bf16 MFMA, K=32 per step.
// LDS tiles are lane-linear: row pitch 32 ushorts (64B) -> conflict-minimal.
#define MFMA_PREAMBLE                                   \
    const int t = threadIdx.x;                          \
    const int wid = t >> 6, l = t & 63;                 \
    const int wm = wid >> 1, wn = wid & 1;              \
    const int l15 = l & 15, lhi = l >> 4;               \
    f32x4 acc[4][4];                                    \
    _Pragma("unroll")                                   \
    for (int a_ = 0; a_ < 4; ++a_)                      \
        _Pragma("unroll")                               \
        for (int b_ = 0; b_ < 4; ++b_)                  \
            acc[a_][b_] = (f32x4){0.f, 0.f, 0.f, 0.f};

#define MFMA_STEP(As, Bs)                                                        \
    {                                                                            \
        bf16x8 af_[4], bf_[4];                                                   \
        _Pragma("unroll")                                                        \
        for (int f_ = 0; f_ < 4; ++f_) {                                         \
            af_[f_] = *(const bf16x8*)((As) + (wm*64 + f_*16 + l15)*32 + lhi*8); \
            bf_[f_] = *(const bf16x8*)((Bs) + (wn*64 + f_*16 + l15)*32 + lhi*8); \
        }                                                                        \
        _Pragma("unroll")                                                        \
        for (int m_ = 0; m_ < 4; ++m_)                                           \
            _Pragma("unroll")                                                    \
            for (int n_ = 0; n_ < 4; ++n_)                                       \
                acc[m_][n_] = __builtin_amdgcn_mfma_f32_16x16x32_bf16(           \
                    af_[m_], bf_[n_], acc[m_][n_], 0, 0, 0);                     \
    }

// ---------------------------------------------------------------------------
// Weights -> n-major bf16 (B-operand layout). Tiny one-off.
// ---------------------------------------------------------------------------
__global__ __launch_bounds__(256) void convert_w(
    const float* __restrict__ Wq, const float* __restrict__ Wk,
    const float* __restrict__ Wv, const float* __restrict__ Wo,
    ushort* __restrict__ WTqkv, ushort* __restrict__ WoT)
{
    const int id = blockIdx.x;      // 0..1023
    const int matn = id >> 8;
    const int n = id & 255;
    const int k = threadIdx.x;
    const float* W = (matn == 0) ? Wq : (matn == 1) ? Wk : (matn == 2) ? Wv : Wo;
    ushort v = f2bf(W[(size_t)k * E_ + n]);
    if (matn < 3) WTqkv[((size_t)matn * E_ + n) * E_ + k] = v;
    else          WoT[(size_t)n * E_ + k] = v;
}

// ---------------------------------------------------------------------------
// Fused QKV projection. 12288 blocks, XCD-chunked; nt (0..5) fastest so the 6
// blocks sharing an x panel sit on one XCD. Reads x fp32 directly (converts
// in-register during A staging). Epilogue repacks through LDS -> uint4 stores;
// v is transposed in LDS ([e][c]) so vb[h][r][d][c] stores are wide.
// ---------------------------------------------------------------------------
__global__ __launch_bounds__(256) void qkv_mfma(
    const float* __restrict__ x, const ushort* __restrict__ WT,
    const float* __restrict__ bq, const float* __restrict__ bk,
    const float* __restrict__ bv, const float* __restrict__ mask,
    ushort* __restrict__ qb, ushort* __restrict__ kb, ushort* __restrict__ vb)
{
    __shared__ __align__(16) ushort S[128 * RP];   // 34816B; aliases staging+repack
    ushort* As = S;           // 128x32, pitch 32
    ushort* Bs = S + 4096;
    const int id = ((blockIdx.x & 7) * 1536) + (blockIdx.x >> 3);
    const int nt = id % 6;
    const int rc0 = (id / 6) * 128;
    MFMA_PREAMBLE;

    const float*  Ab = x + (size_t)rc0 * E_;
    const ushort* Bb = WT + (size_t)nt * 128 * E_;

    for (int it = 0; it < 8; ++it) {
        #pragma unroll
        for (int c = 0; c < 2; ++c) {
            const int f = t + 256 * c;
            const int row = f >> 2, ko = (f & 3) * 8;
            const float* src = Ab + (size_t)row * E_ + it * 32 + ko;
            float4 a = *(const float4*)src;
            float4 b = *(const float4*)(src + 4);
            ushort o[8] = {f2bf(a.x), f2bf(a.y), f2bf(a.z), f2bf(a.w),
                           f2bf(b.x), f2bf(b.y), f2bf(b.z), f2bf(b.w)};
            *(uint4*)(As + f * 8) = *(uint4*)o;
            gll16(Bb + (size_t)row * E_ + it * 32 + ko, Bs + f * 8);
        }
        __syncthreads();
        MFMA_STEP(As, Bs);
        __syncthreads();
    }

    const int proj = nt >> 1;
    const float* bias = (proj == 0) ? bq : (proj == 1) ? bk : bv;
    float bvv[4];
    #pragma unroll
    for (int fn = 0; fn < 4; ++fn)
        bvv[fn] = bias[(nt * 128 + wn * 64 + fn * 16 + l15) & 255];

    // repack: q/k as [c][e], v as [e][c]
    #pragma unroll
    for (int fm = 0; fm < 4; ++fm)
        #pragma unroll
        for (int fn = 0; fn < 4; ++fn)
            #pragma unroll
            for (int rg = 0; rg < 4; ++rg) {
                const int m = wm * 64 + fm * 16 + lhi * 4 + rg;
                const int n = wn * 64 + fn * 16 + l15;
                const ushort val = f2bf(acc[fm][fn][rg] + bvv[fn]);
                if (proj < 2) S[m * RP + n] = val;
                else          S[n * RP + m] = val;
            }
    __syncthreads();

    const int r = rc0 >> 9, c0 = rc0 & 511;
    if (proj < 2) {
        ushort* dst = (proj == 0) ? qb : kb;
        #pragma unroll
        for (int c = 0; c < 8; ++c) {
            const int idx = t + 256 * c;
            const int mrow = idx >> 4, ne = (idx & 15) * 8;
            uint4 w = *(const uint4*)(S + mrow * RP + ne);
            if (proj == 0) {   // q: * 1/128 * (1-mask)  (exact pow2 scale)
                const float sk = 0.0078125f * (1.0f - mask[rc0 + mrow]);
                ushort* ws = (ushort*)&w;
                #pragma unroll
                for (int jj = 0; jj < 8; ++jj) ws[jj] = f2bf(bf2f(ws[jj]) * sk);
            }
            const int e = (nt & 1) * 128 + ne, h = e >> 5, d = e & 31;
            *(uint4*)(dst + ((((size_t)h * R_ + r) * C_) + c0 + mrow) * D_ + d) = w;
        }
    } else {
        #pragma unroll
        for (int c = 0; c < 8; ++c) {
            const int idx = t + 256 * c;
            const int nrow = idx >> 4, m0 = (idx & 15) * 8;
            uint4 w = *(const uint4*)(S + nrow * RP + m0);
            const int e = (nt & 1) * 128 + nrow, h = e >> 5, d = e & 31;
            *(uint4*)(vb + (((size_t)h * R_ + r) * D_ + d) * C_ + c0 + m0) = w;
        }
    }
}

// ---------------------------------------------------------------------------
// Attention logits. K = R*D split 8-way over r (1024 blocks). Tiles are fully
// contiguous 8KB -> pure global_load_lds staging.
// ---------------------------------------------------------------------------
__global__ __launch_bounds__(256) void logits_mfma(
    const ushort* __restrict__ qb, const ushort* __restrict__ kb,
    float* __restrict__ partial)
{
    __shared__ __align__(16) ushort S[8192];
    ushort* As = S;
    ushort* Bs = S + 4096;
    const int id = ((blockIdx.x & 7) * 128) + (blockIdx.x >> 3);
    const int sub = id & 15;
    const int j0 = (sub & 3) * 128;         // j fastest: 4 blocks share q panel
    const int i0 = (sub >> 2) * 128;
    const int hks = id >> 4;                // 0..63
    const int h = hks >> 3, ks = hks & 7;
    MFMA_PREAMBLE;

    for (int it = 0; it < 64; ++it) {
        const int rr = ks * 64 + it;
        const ushort* Ab = qb + (((size_t)h * R_ + rr) * C_ + i0) * D_;
        const ushort* Bb = kb + (((size_t)h * R_ + rr) * C_ + j0) * D_;
        #pragma unroll
        for (int c = 0; c < 2; ++c) {
            const int f = t + 256 * c;
            gll16(Ab + f * 8, As + f * 8);
            gll16(Bb + f * 8, Bs + f * 8);
        }
        __syncthreads();
        MFMA_STEP(As, Bs);
        __syncthreads();
    }

    float* dst = partial + ((size_t)ks * H_ + h) * C_ * C_;
    #pragma unroll
    for (int fm = 0; fm < 4; ++fm)
        #pragma unroll
        for (int rg = 0; rg < 4; ++rg) {
            const int i = i0 + wm * 64 + fm * 16 + lhi * 4 + rg;
            #pragma unroll
            for (int fn = 0; fn < 4; ++fn) {
                const int j = j0 + wn * 64 + fn * 16 + l15;
                dst[(size_t)i * C_ + j] = acc[fm][fn][rg];
            }
        }
}

// ---------------------------------------------------------------------------
// Sum 8 K-split partials + i-axis mask + softmax over j. fp32 probs out +
// bf16 copy for the context GEMM.
// ---------------------------------------------------------------------------
__global__ __launch_bounds__(256) void softmax_kernel(
    const float* __restrict__ partial, const float* __restrict__ mask,
    float* __restrict__ probs, ushort* __restrict__ Pb)
{
    const int hi = blockIdx.x;
    const int i = hi & 511;
    const int t = threadIdx.x;
    const size_t base = (size_t)hi * C_;
    const size_t stride = (size_t)H_ * C_ * C_;
    float v0 = 0.f, v1 = 0.f;
    #pragma unroll
    for (int ksp = 0; ksp < 8; ++ksp) {
        v0 += partial[ksp * stride + base + t];
        v1 += partial[ksp * stride + base + t + 256];
    }
    const float mi = mask[i];
    const float keep = 1.0f - mi;
    v0 = v0 * keep + mi * (-10000.0f);
    v1 = v1 * keep + mi * (-10000.0f);

    float m = fmaxf(v0, v1);
    #pragma unroll
    for (int off = 32; off > 0; off >>= 1) m = fmaxf(m, __shfl_xor(m, off));
    __shared__ float red[4];
    if ((t & 63) == 0) red[t >> 6] = m;
    __syncthreads();
    m = fmaxf(fmaxf(red[0], red[1]), fmaxf(red[2], red[3]));

    const float e0 = expf(v0 - m), e1 = expf(v1 - m);
    float s = e0 + e1;
    #pragma unroll
    for (int off = 32; off > 0; off >>= 1) s += __shfl_xor(s, off);
    __syncthreads();
    if ((t & 63) == 0) red[t >> 6] = s;
    __syncthreads();
    s = red[0] + red[1] + red[2] + red[3];

    const float inv = 1.0f / s;
    const float p0 = e0 * inv, p1 = e1 * inv;
    probs[base + t] = p0;
    probs[base + t + 256] = p1;
    Pb[base + t] = f2bf(p0);
    Pb[base + t + 256] = f2bf(p1);
}

// ---------------------------------------------------------------------------
// Context: per head, ctx[i, n=(r,d)] = sum_j P[i,j] * vb[h][n][j].
// 4096 blocks XCD-chunked (one head per XCD). LDS-repacked wide stores.
// ---------------------------------------------------------------------------
__global__ __launch_bounds__(256) void context_mfma(
    const ushort* __restrict__ Pb, const ushort* __restrict__ vb,
    ushort* __restrict__ ctxb)
{
    __shared__ __align__(16) ushort S[128 * RP];
    ushort* As = S;
    ushort* Bs = S + 4096;
    const int id = ((blockIdx.x & 7) * 512) + (blockIdx.x >> 3);
    const int i0 = (id & 3) * 128;          // i fastest: 4 blocks share vb panel
    const int n0 = ((id >> 2) & 127) * 128;
    const int h = id >> 9;
    MFMA_PREAMBLE;

    const ushort* Ab = Pb + ((size_t)h * C_ + i0) * C_;
    const ushort* Bb = vb + ((size_t)h * R_ * D_ + n0) * C_;

    for (int it = 0; it < 16; ++it) {
        #pragma unroll
        for (int c = 0; c < 2; ++c) {
            const int f = t + 256 * c;
            const int row = f >> 2, ko = (f & 3) * 8;
            gll16(Ab + (size_t)row * C_ + it * 32 + ko, As + f * 8);
            gll16(Bb + (size_t)row * C_ + it * 32 + ko, Bs + f * 8);
        }
        __syncthreads();
        MFMA_STEP(As, Bs);
        __syncthreads();
    }

    #pragma unroll
    for (int fm = 0; fm < 4; ++fm)
        #pragma unroll
        for (int fn = 0; fn < 4; ++fn)
            #pragma unroll
            for (int rg = 0; rg < 4; ++rg) {
                const int m = wm * 64 + fm * 16 + lhi * 4 + rg;
                const int n = wn * 64 + fn * 16 + l15;
                S[m * RP + n] = f2bf(acc[fm][fn][rg]);
            }
    __syncthreads();

    #pragma unroll
    for (int c = 0; c < 8; ++c) {
        const int idx = t + 256 * c;
        const int mrow = idx >> 4, nl = (idx & 15) * 8;
        uint4 w = *(const uint4*)(S + mrow * RP + nl);
        const int n = n0 + nl;
        const int rr = n >> 5, d = n & 31;
        const size_t rc = (size_t)rr * C_ + i0 + mrow;
        *(uint4*)(ctxb + rc * E_ + h * D_ + d) = w;
    }
}

// ---------------------------------------------------------------------------
// Output projection: out = ctx @ Wo + bo, fp32 out via 2-phase LDS repack.
// ---------------------------------------------------------------------------
__global__ __launch_bounds__(256) void out_proj_mfma(
    const ushort* __restrict__ ctxb, const ushort* __restrict__ WoT,
    const float* __restrict__ bo, float* __restrict__ out)
{
    __shared__ __align__(16) ushort S[128 * RP];
    ushort* As = S;
    ushort* Bs = S + 4096;
    float* Sf = (float*)S;                  // 128 x 68 fp32 repack
    const int id = ((blockIdx.x & 7) * 512) + (blockIdx.x >> 3);
    const int n0 = (id & 1) * 128;
    const int rc0 = (id >> 1) * 128;
    MFMA_PREAMBLE;

    const ushort* Ab = ctxb + (size_t)rc0 * E_;
    const ushort* Bb = WoT + (size_t)n0 * E_;

    for (int it = 0; it < 8; ++it) {
        #pragma unroll
        for (int c = 0; c < 2; ++c) {
            const int f = t + 256 * c;
            const int row = f >> 2, ko = (f & 3) * 8;
            gll16(Ab + (size_t)row * E_ + it * 32 + ko, As + f * 8);
            gll16(Bb + (size_t)row * E_ + it * 32 + ko, Bs + f * 8);
        }
        __syncthreads();
        MFMA_STEP(As, Bs);
        __syncthreads();
    }

    float bvv[4];
    #pragma unroll
    for (int fn = 0; fn < 4; ++fn)
        bvv[fn] = bo[n0 + wn * 64 + fn * 16 + l15];

    #pragma unroll
    for (int p = 0; p < 2; ++p) {
        #pragma unroll
        for (int fm = 0; fm < 4; ++fm)
            #pragma unroll
            for (int fh = 0; fh < 2; ++fh) {
                const int fn = 2 * p + fh;
                #pragma unroll
                for (int rg = 0; rg < 4; ++rg) {
                    const int m = wm * 64 + fm * 16 + lhi * 4 + rg;
                    const int s = wn * 32 + fh * 16 + l15;
                    Sf[m * 68 + s] = acc[fm][fn][rg] + bvv[fn];
                }
            }
        __syncthreads();
        #pragma unroll
        for (int c = 0; c < 8; ++c) {
            const int idx = t + 256 * c;
            const int row = idx >> 4, s0 = (idx & 15) * 4;
            float4 w = *(const float4*)(Sf + row * 68 + s0);
            const int ncol = n0 + (s0 >> 5) * 64 + (2 * p + ((s0 >> 4) & 1)) * 16 + (s0 & 15);
            *(float4*)(out + ((size_t)rc0 + row) * E_ + ncol) = w;
        }
        __syncthreads();
    }
}

// ---------------------------------------------------------------------------
extern "C" void kernel_launch(void* const* d_in, const int* in_sizes, int n_in,
                              void* d_out, int out_size, void* d_ws, size_t ws_size,
                              hipStream_t stream)
{
    const float* x    = (const float*)d_in[0];
    const float* mask = (const float*)d_in[1];
    const float* Wq   = (const float*)d_in[2];
    const float* bq   = (const float*)d_in[3];
    const float* Wk   = (const float*)d_in[4];
    const float* bk   = (const float*)d_in[5];
    const float* Wv   = (const float*)d_in[6];
    const float* bv   = (const float*)d_in[7];
    const float* Wo   = (const float*)d_in[8];
    const float* bo   = (const float*)d_in[9];

    float* out   = (float*)d_out;                       // [R,C,E] fp32
    float* probs = out + (size_t)RC_ * E_;              // [H,C,C] fp32

    char* ws = (char*)d_ws;
    ushort* qb      = (ushort*)(ws);                    // 128 MB  [h][r][c][d]
    ushort* kb      = (ushort*)(ws + 134217728ull);     // 128 MB  [h][r][c][d]
    ushort* vb      = (ushort*)(ws + 268435456ull);     // 128 MB  [h][r][d][c]
    ushort* ctxb    = (ushort*)(ws + 402653184ull);     // 128 MB  [rc][e]
    float*  partial = (float*)(ws + 536870912ull);      // 64 MB   [8][h][i][j]
    ushort* Pb      = (ushort*)(ws + 603979776ull);     // 4 MB    [h][i][j]
    ushort* WTqkv   = (ushort*)(ws + 608174080ull);     // 384 KB
    ushort* WoT     = (ushort*)(ws + 608567296ull);     // 128 KB

    convert_w<<<1024, 256, 0, stream>>>(Wq, Wk, Wv, Wo, WTqkv, WoT);
    qkv_mfma<<<12288, 256, 0, stream>>>(x, WTqkv, bq, bk, bv, mask, qb, kb, vb);
    logits_mfma<<<1024, 256, 0, stream>>>(qb, kb, partial);
    softmax_kernel<<<4096, 256, 0, stream>>>(partial, mask, probs, Pb);
    context_mfma<<<4096, 256, 0, stream>>>(Pb, vb, ctxb);
    out_proj_mfma<<<4096, 256, 0, stream>>>(ctxb, WoT, bo, out);
}

// Round 4
// 714.147 us; speedup vs baseline: 5.8274x; 1.0002x over previous
//
#include <hip/hip_runtime.h>
#include <math.h>

#define R_ 512
#define C_ 512
#define E_ 256
#define H_ 8
#define D_ 32
#define RC_ (R_*C_)   // 262144
#define RP 136        // repack pitch (ushorts); mult of 8, breaks power-of-2 banks

typedef __attribute__((ext_vector_type(8))) short bf16x8;
typedef __attribute__((ext_vector_type(4))) float f32x4;

__device__ __forceinline__ ushort f2bf(float f) {
    union { float f; unsigned u; } v; v.f = f;
    unsigned r = v.u + 0x7FFFu + ((v.u >> 16) & 1u);   // RNE
    return (ushort)(r >> 16);
}
__device__ __forceinline__ float bf2f(ushort u) {
    union { unsigned u; float f; } v; v.u = ((unsigned)u) << 16;
    return v.f;
}

// 16B global->LDS direct copy (lane-linear dest), fallback = reg staging.
__device__ __forceinline__ void gll16(const ushort* g, ushort* l) {
#if __has_builtin(__builtin_amdgcn_global_load_lds)
    __builtin_amdgcn_global_load_lds(
        (const __attribute__((address_space(1))) unsigned*)(unsigned long long)g,
        (__attribute__((address_space(3))) unsigned*)(unsigned)(unsigned long long)l,
        16, 0, 0);
#else
    *(uint4*)l = *(const uint4*)g;
#endif
}

// 128x128 tile, 4 waves (2x2), 16x16x32 bf16 MFMA, K=32 per step.
// LDS tiles are lane-linear: row pitch 32 ushorts (64B) -> conflict-minimal.
#define MFMA_PREAMBLE                                   \
    const int t = threadIdx.x;                          \
    const int wid = t >> 6, l = t & 63;                 \
    const int wm = wid >> 1, wn = wid & 1;              \
    const int l15 = l & 15, lhi = l >> 4;               \
    f32x4 acc[4][4];                                    \
    _Pragma("unroll")                                   \
    for (int a_ = 0; a_ < 4; ++a_)                      \
        _Pragma("unroll")                               \
        for (int b_ = 0; b_ < 4; ++b_)                  \
            acc[a_][b_] = (f32x4){0.f, 0.f, 0.f, 0.f};

#define MFMA_STEP(As, Bs)                                                        \
    {                                                                            \
        bf16x8 af_[4], bf_[4];                                                   \
        _Pragma("unroll")                                                        \
        for (int f_ = 0; f_ < 4; ++f_) {                                         \
            af_[f_] = *(const bf16x8*)((As) + (wm*64 + f_*16 + l15)*32 + lhi*8); \
            bf_[f_] = *(const bf16x8*)((Bs) + (wn*64 + f_*16 + l15)*32 + lhi*8); \
        }                                                                        \
        _Pragma("unroll")                                                        \
        for (int m_ = 0; m_ < 4; ++m_)                                           \
            _Pragma("unroll")                                                    \
            for (int n_ = 0; n_ < 4; ++n_)                                       \
                acc[m_][n_] = __builtin_amdgcn_mfma_f32_16x16x32_bf16(           \
                    af_[m_], bf_[n_], acc[m_][n_], 0, 0, 0);                     \
    }

// ---------------------------------------------------------------------------
// x fp32 -> bf16, once. Coalesced: float4 loads / uint2 stores per slot.
// ---------------------------------------------------------------------------
__global__ __launch_bounds__(256) void convert_x(
    const float* __restrict__ x, ushort* __restrict__ xb)
{
    const size_t blk = (size_t)blockIdx.x * 4096;
    #pragma unroll
    for (int c = 0; c < 4; ++c) {
        const size_t s = blk + ((size_t)threadIdx.x + 256 * c) * 4;
        float4 a = *(const float4*)(x + s);
        ushort o[4] = {f2bf(a.x), f2bf(a.y), f2bf(a.z), f2bf(a.w)};
        *(uint2*)(xb + s) = *(uint2*)o;
    }
}

// ---------------------------------------------------------------------------
// Weights -> n-major bf16 (B-operand layout). Tiny one-off.
// ---------------------------------------------------------------------------
__global__ __launch_bounds__(256) void convert_w(
    const float* __restrict__ Wq, const float* __restrict__ Wk,
    const float* __restrict__ Wv, const float* __restrict__ Wo,
    ushort* __restrict__ WTqkv, ushort* __restrict__ WoT)
{
    const int id = blockIdx.x;      // 0..1023
    const int matn = id >> 8;
    const int n = id & 255;
    const int k = threadIdx.x;
    const float* W = (matn == 0) ? Wq : (matn == 1) ? Wk : (matn == 2) ? Wv : Wo;
    ushort v = f2bf(W[(size_t)k * E_ + n]);
    if (matn < 3) WTqkv[((size_t)matn * E_ + n) * E_ + k] = v;
    else          WoT[(size_t)n * E_ + k] = v;
}

// ---------------------------------------------------------------------------
// Fused QKV projection. 12288 blocks, XCD-chunked; nt (0..5) fastest so the 6
// blocks sharing an x panel sit on one XCD. Pure global_load_lds staging (xb
// is pre-converted bf16). Epilogue repacks through LDS -> uint4 stores; v is
// transposed in LDS ([e][c]) so vb[h][r][d][c] stores are wide.
// ---------------------------------------------------------------------------
__global__ __launch_bounds__(256) void qkv_mfma(
    const ushort* __restrict__ xb, const ushort* __restrict__ WT,
    const float* __restrict__ bq, const float* __restrict__ bk,
    const float* __restrict__ bv, const float* __restrict__ mask,
    ushort* __restrict__ qb, ushort* __restrict__ kb, ushort* __restrict__ vb)
{
    __shared__ __align__(16) ushort S[128 * RP];   // 34816B; aliases staging+repack
    ushort* As = S;           // 128x32, pitch 32
    ushort* Bs = S + 4096;
    const int id = ((blockIdx.x & 7) * 1536) + (blockIdx.x >> 3);
    const int nt = id % 6;
    const int rc0 = (id / 6) * 128;
    MFMA_PREAMBLE;

    const ushort* Ab = xb + (size_t)rc0 * E_;
    const ushort* Bb = WT + (size_t)nt * 128 * E_;

    for (int it = 0; it < 8; ++it) {
        #pragma unroll
        for (int c = 0; c < 2; ++c) {
            const int f = t + 256 * c;
            const int row = f >> 2, ko = (f & 3) * 8;
            gll16(Ab + (size_t)row * E_ + it * 32 + ko, As + f * 8);
            gll16(Bb + (size_t)row * E_ + it * 32 + ko, Bs + f * 8);
        }
        __syncthreads();
        MFMA_STEP(As, Bs);
        __syncthreads();
    }

    const int proj = nt >> 1;
    const float* bias = (proj == 0) ? bq : (proj == 1) ? bk : bv;
    float bvv[4];
    #pragma unroll
    for (int fn = 0; fn < 4; ++fn)
        bvv[fn] = bias[(nt * 128 + wn * 64 + fn * 16 + l15) & 255];

    // repack: q/k as [c][e], v as [e][c]
    #pragma unroll
    for (int fm = 0; fm < 4; ++fm)
        #pragma unroll
        for (int fn = 0; fn < 4; ++fn)
            #pragma unroll
            for (int rg = 0; rg < 4; ++rg) {
                const int m = wm * 64 + fm * 16 + lhi * 4 + rg;
                const int n = wn * 64 + fn * 16 + l15;
                const ushort val = f2bf(acc[fm][fn][rg] + bvv[fn]);
                if (proj < 2) S[m * RP + n] = val;
                else          S[n * RP + m] = val;
            }
    __syncthreads();

    const int r = rc0 >> 9, c0 = rc0 & 511;
    if (proj < 2) {
        ushort* dst = (proj == 0) ? qb : kb;
        #pragma unroll
        for (int c = 0; c < 8; ++c) {
            const int idx = t + 256 * c;
            const int mrow = idx >> 4, ne = (idx & 15) * 8;
            uint4 w = *(const uint4*)(S + mrow * RP + ne);
            if (proj == 0) {   // q: * 1/128 * (1-mask)  (exact pow2 scale)
                const float sk = 0.0078125f * (1.0f - mask[rc0 + mrow]);
                ushort* ws = (ushort*)&w;
                #pragma unroll
                for (int jj = 0; jj < 8; ++jj) ws[jj] = f2bf(bf2f(ws[jj]) * sk);
            }
            const int e = (nt & 1) * 128 + ne, h = e >> 5, d = e & 31;
            *(uint4*)(dst + ((((size_t)h * R_ + r) * C_) + c0 + mrow) * D_ + d) = w;
        }
    } else {
        #pragma unroll
        for (int c = 0; c < 8; ++c) {
            const int idx = t + 256 * c;
            const int nrow = idx >> 4, m0 = (idx & 15) * 8;
            uint4 w = *(const uint4*)(S + nrow * RP + m0);
            const int e = (nt & 1) * 128 + nrow, h = e >> 5, d = e & 31;
            *(uint4*)(vb + (((size_t)h * R_ + r) * D_ + d) * C_ + c0 + m0) = w;
        }
    }
}

// ---------------------------------------------------------------------------
// Attention logits. K = R*D split 8-way over r (1024 blocks). Tiles are fully
// contiguous 8KB -> pure global_load_lds staging.
// ---------------------------------------------------------------------------
__global__ __launch_bounds__(256) void logits_mfma(
    const ushort* __restrict__ qb, const ushort* __restrict__ kb,
    float* __restrict__ partial)
{
    __shared__ __align__(16) ushort S[8192];
    ushort* As = S;
    ushort* Bs = S + 4096;
    const int id = ((blockIdx.x & 7) * 128) + (blockIdx.x >> 3);
    const int sub = id & 15;
    const int j0 = (sub & 3) * 128;         // j fastest: 4 blocks share q panel
    const int i0 = (sub >> 2) * 128;
    const int hks = id >> 4;                // 0..63
    const int h = hks >> 3, ks = hks & 7;
    MFMA_PREAMBLE;

    for (int it = 0; it < 64; ++it) {
        const int rr = ks * 64 + it;
        const ushort* Ab = qb + (((size_t)h * R_ + rr) * C_ + i0) * D_;
        const ushort* Bb = kb + (((size_t)h * R_ + rr) * C_ + j0) * D_;
        #pragma unroll
        for (int c = 0; c < 2; ++c) {
            const int f = t + 256 * c;
            gll16(Ab + f * 8, As + f * 8);
            gll16(Bb + f * 8, Bs + f * 8);
        }
        __syncthreads();
        MFMA_STEP(As, Bs);
        __syncthreads();
    }

    float* dst = partial + ((size_t)ks * H_ + h) * C_ * C_;
    #pragma unroll
    for (int fm = 0; fm < 4; ++fm)
        #pragma unroll
        for (int rg = 0; rg < 4; ++rg) {
            const int i = i0 + wm * 64 + fm * 16 + lhi * 4 + rg;
            #pragma unroll
            for (int fn = 0; fn < 4; ++fn) {
                const int j = j0 + wn * 64 + fn * 16 + l15;
                dst[(size_t)i * C_ + j] = acc[fm][fn][rg];
            }
        }
}

// ---------------------------------------------------------------------------
// Sum 8 K-split partials + i-axis mask + softmax over j. fp32 probs out +
// bf16 copy for the context GEMM.
// ---------------------------------------------------------------------------
__global__ __launch_bounds__(256) void softmax_kernel(
    const float* __restrict__ partial, const float* __restrict__ mask,
    float* __restrict__ probs, ushort* __restrict__ Pb)
{
    const int hi = blockIdx.x;
    const int i = hi & 511;
    const int t = threadIdx.x;
    const size_t base = (size_t)hi * C_;
    const size_t stride = (size_t)H_ * C_ * C_;
    float v0 = 0.f, v1 = 0.f;
    #pragma unroll
    for (int ksp = 0; ksp < 8; ++ksp) {
        v0 += partial[ksp * stride + base + t];
        v1 += partial[ksp * stride + base + t + 256];
    }
    const float mi = mask[i];
    const float keep = 1.0f - mi;
    v0 = v0 * keep + mi * (-10000.0f);
    v1 = v1 * keep + mi * (-10000.0f);

    float m = fmaxf(v0, v1);
    #pragma unroll
    for (int off = 32; off > 0; off >>= 1) m = fmaxf(m, __shfl_xor(m, off));
    __shared__ float red[4];
    if ((t & 63) == 0) red[t >> 6] = m;
    __syncthreads();
    m = fmaxf(fmaxf(red[0], red[1]), fmaxf(red[2], red[3]));

    const float e0 = expf(v0 - m), e1 = expf(v1 - m);
    float s = e0 + e1;
    #pragma unroll
    for (int off = 32; off > 0; off >>= 1) s += __shfl_xor(s, off);
    __syncthreads();
    if ((t & 63) == 0) red[t >> 6] = s;
    __syncthreads();
    s = red[0] + red[1] + red[2] + red[3];

    const float inv = 1.0f / s;
    const float p0 = e0 * inv, p1 = e1 * inv;
    probs[base + t] = p0;
    probs[base + t + 256] = p1;
    Pb[base + t] = f2bf(p0);
    Pb[base + t + 256] = f2bf(p1);
}

// ---------------------------------------------------------------------------
// Context: per head, ctx[i, n=(r,d)] = sum_j P[i,j] * vb[h][n][j].
// 4096 blocks XCD-chunked (one head per XCD). LDS-repacked wide stores.
// ---------------------------------------------------------------------------
__global__ __launch_bounds__(256) void context_mfma(
    const ushort* __restrict__ Pb, const ushort* __restrict__ vb,
    ushort* __restrict__ ctxb)
{
    __shared__ __align__(16) ushort S[128 * RP];
    ushort* As = S;
    ushort* Bs = S + 4096;
    const int id = ((blockIdx.x & 7) * 512) + (blockIdx.x >> 3);
    const int i0 = (id & 3) * 128;          // i fastest: 4 blocks share vb panel
    const int n0 = ((id >> 2) & 127) * 128;
    const int h = id >> 9;
    MFMA_PREAMBLE;

    const ushort* Ab = Pb + ((size_t)h * C_ + i0) * C_;
    const ushort* Bb = vb + ((size_t)h * R_ * D_ + n0) * C_;

    for (int it = 0; it < 16; ++it) {
        #pragma unroll
        for (int c = 0; c < 2; ++c) {
            const int f = t + 256 * c;
            const int row = f >> 2, ko = (f & 3) * 8;
            gll16(Ab + (size_t)row * C_ + it * 32 + ko, As + f * 8);
            gll16(Bb + (size_t)row * C_ + it * 32 + ko, Bs + f * 8);
        }
        __syncthreads();
        MFMA_STEP(As, Bs);
        __syncthreads();
    }

    #pragma unroll
    for (int fm = 0; fm < 4; ++fm)
        #pragma unroll
        for (int fn = 0; fn < 4; ++fn)
            #pragma unroll
            for (int rg = 0; rg < 4; ++rg) {
                const int m = wm * 64 + fm * 16 + lhi * 4 + rg;
                const int n = wn * 64 + fn * 16 + l15;
                S[m * RP + n] = f2bf(acc[fm][fn][rg]);
            }
    __syncthreads();

    #pragma unroll
    for (int c = 0; c < 8; ++c) {
        const int idx = t + 256 * c;
        const int mrow = idx >> 4, nl = (idx & 15) * 8;
        uint4 w = *(const uint4*)(S + mrow * RP + nl);
        const int n = n0 + nl;
        const int rr = n >> 5, d = n & 31;
        const size_t rc = (size_t)rr * C_ + i0 + mrow;
        *(uint4*)(ctxb + rc * E_ + h * D_ + d) = w;
    }
}

// ---------------------------------------------------------------------------
// Output projection: out = ctx @ Wo + bo, fp32 out via 2-phase LDS repack.
// ---------------------------------------------------------------------------
__global__ __launch_bounds__(256) void out_proj_mfma(
    const ushort* __restrict__ ctxb, const ushort* __restrict__ WoT,
    const float* __restrict__ bo, float* __restrict__ out)
{
    __shared__ __align__(16) ushort S[128 * RP];
    ushort* As = S;
    ushort* Bs = S + 4096;
    float* Sf = (float*)S;                  // 128 x 68 fp32 repack
    const int id = ((blockIdx.x & 7) * 512) + (blockIdx.x >> 3);
    const int n0 = (id & 1) * 128;
    const int rc0 = (id >> 1) * 128;
    MFMA_PREAMBLE;

    const ushort* Ab = ctxb + (size_t)rc0 * E_;
    const ushort* Bb = WoT + (size_t)n0 * E_;

    for (int it = 0; it < 8; ++it) {
        #pragma unroll
        for (int c = 0; c < 2; ++c) {
            const int f = t + 256 * c;
            const int row = f >> 2, ko = (f & 3) * 8;
            gll16(Ab + (size_t)row * E_ + it * 32 + ko, As + f * 8);
            gll16(Bb + (size_t)row * E_ + it * 32 + ko, Bs + f * 8);
        }
        __syncthreads();
        MFMA_STEP(As, Bs);
        __syncthreads();
    }

    float bvv[4];
    #pragma unroll
    for (int fn = 0; fn < 4; ++fn)
        bvv[fn] = bo[n0 + wn * 64 + fn * 16 + l15];

    #pragma unroll
    for (int p = 0; p < 2; ++p) {
        #pragma unroll
        for (int fm = 0; fm < 4; ++fm)
            #pragma unroll
            for (int fh = 0; fh < 2; ++fh) {
                const int fn = 2 * p + fh;
                #pragma unroll
                for (int rg = 0; rg < 4; ++rg) {
                    const int m = wm * 64 + fm * 16 + lhi * 4 + rg;
                    const int s = wn * 32 + fh * 16 + l15;
                    Sf[m * 68 + s] = acc[fm][fn][rg] + bvv[fn];
                }
            }
        __syncthreads();
        #pragma unroll
        for (int c = 0; c < 8; ++c) {
            const int idx = t + 256 * c;
            const int row = idx >> 4, s0 = (idx & 15) * 4;
            float4 w = *(const float4*)(Sf + row * 68 + s0);
            const int ncol = n0 + (s0 >> 5) * 64 + (2 * p + ((s0 >> 4) & 1)) * 16 + (s0 & 15);
            *(float4*)(out + ((size_t)rc0 + row) * E_ + ncol) = w;
        }
        __syncthreads();
    }
}

// ---------------------------------------------------------------------------
extern "C" void kernel_launch(void* const* d_in, const int* in_sizes, int n_in,
                              void* d_out, int out_size, void* d_ws, size_t ws_size,
                              hipStream_t stream)
{
    const float* x    = (const float*)d_in[0];
    const float* mask = (const float*)d_in[1];
    const float* Wq   = (const float*)d_in[2];
    const float* bq   = (const float*)d_in[3];
    const float* Wk   = (const float*)d_in[4];
    const float* bk   = (const float*)d_in[5];
    const float* Wv   = (const float*)d_in[6];
    const float* bv   = (const float*)d_in[7];
    const float* Wo   = (const float*)d_in[8];
    const float* bo   = (const float*)d_in[9];

    float* out   = (float*)d_out;                       // [R,C,E] fp32
    float* probs = out + (size_t)RC_ * E_;              // [H,C,C] fp32

    char* ws = (char*)d_ws;
    ushort* qb      = (ushort*)(ws);                    // 128 MB  [h][r][c][d]
    ushort* kb      = (ushort*)(ws + 134217728ull);     // 128 MB  [h][r][c][d]
    ushort* vb      = (ushort*)(ws + 268435456ull);     // 128 MB  [h][r][d][c]
    ushort* ctxb    = (ushort*)(ws + 402653184ull);     // 128 MB  [rc][e]
    float*  partial = (float*)(ws + 536870912ull);      // 64 MB   [8][h][i][j]
    ushort* Pb      = (ushort*)(ws + 603979776ull);     // 4 MB    [h][i][j]
    ushort* WTqkv   = (ushort*)(ws + 608174080ull);     // 384 KB
    ushort* WoT     = (ushort*)(ws + 608567296ull);     // 128 KB
    ushort* xb      = (ushort*)(ws + 608700416ull);     // 128 MB  [rc][e]

    convert_x<<<16384, 256, 0, stream>>>(x, xb);
    convert_w<<<1024, 256, 0, stream>>>(Wq, Wk, Wv, Wo, WTqkv, WoT);
    qkv_mfma<<<12288, 256, 0, stream>>>(xb, WTqkv, bq, bk, bv, mask, qb, kb, vb);
    logits_mfma<<<1024, 256, 0, stream>>>(qb, kb, partial);
    softmax_kernel<<<4096, 256, 0, stream>>>(partial, mask, probs, Pb);
    context_mfma<<<4096, 256, 0, stream>>>(Pb, vb, ctxb);
    out_proj_mfma<<<4096, 256, 0, stream>>>(ctxb, WoT, bo, out);
}

// Round 6
// 697.531 us; speedup vs baseline: 5.9662x; 1.0238x over previous
//
#include <hip/hip_runtime.h>
#include <math.h>

#define R_ 512
#define C_ 512
#define E_ 256
#define H_ 8
#define D_ 32
#define RC_ (R_*C_)   // 262144
#define RP 136        // repack pitch (ushorts); mult of 8, breaks power-of-2 banks

typedef __attribute__((ext_vector_type(8))) short bf16x8;
typedef __attribute__((ext_vector_type(4))) float f32x4;

__device__ __forceinline__ ushort f2bf(float f) {
    union { float f; unsigned u; } v; v.f = f;
    unsigned r = v.u + 0x7FFFu + ((v.u >> 16) & 1u);   // RNE
    return (ushort)(r >> 16);
}
__device__ __forceinline__ float bf2f(ushort u) {
    union { unsigned u; float f; } v; v.u = ((unsigned)u) << 16;
    return v.f;
}

// 16B global->LDS direct copy (lane-linear dest), fallback = reg staging.
__device__ __forceinline__ void gll16(const ushort* g, ushort* l) {
#if __has_builtin(__builtin_amdgcn_global_load_lds)
    __builtin_amdgcn_global_load_lds(
        (const __attribute__((address_space(1))) unsigned*)(unsigned long long)g,
        (__attribute__((address_space(3))) unsigned*)(unsigned)(unsigned long long)l,
        16, 0, 0);
#else
    *(uint4*)l = *(const uint4*)g;
#endif
}

// Stage a 128x32 tile pair into LDS buffers. Source 16B-slot is XOR-swizzled
// by (row&3) (involution) so the matching swizzled fragment read is ~4-way
// conflict-free instead of 8-way.  LDS dest stays lane-linear (gll req).
__device__ __forceinline__ void stage2(const ushort* Ab, int strideA,
                                       const ushort* Bb, int strideB,
                                       ushort* As_, ushort* Bs_, int t) {
    #pragma unroll
    for (int c = 0; c < 2; ++c) {
        const int f = t + 256 * c;
        const int row = f >> 2;
        const int ko = ((f & 3) ^ (row & 3)) * 8;
        gll16(Ab + (size_t)row * strideA + ko, As_ + f * 8);
        gll16(Bb + (size_t)row * strideB + ko, Bs_ + f * 8);
    }
}

// __syncthreads: compiler emits the full vmcnt/lgkmcnt drain before s_barrier
// (proper fence — raw s_barrier is IntrNoMem and allows ds_read hoisting,
// which raced in the previous round).
#define SYNCV __syncthreads()

#define BUFS ushort* A0 = S; ushort* B0 = S + 4096;                  \
             ushort* A1 = S + 8192; ushort* B1 = S + 12288;

// 128x128 tile, 4 waves (2x2), 16x16x32 bf16 MFMA, K=32 per step.
#define MFMA_PREAMBLE                                   \
    const int t = threadIdx.x;                          \
    const int wid = t >> 6, l = t & 63;                 \
    const int wm = wid >> 1, wn = wid & 1;              \
    const int l15 = l & 15, lhi = l >> 4;               \
    const int swz8 = (lhi ^ (l15 & 3)) * 8;             \
    f32x4 acc[4][4];                                    \
    _Pragma("unroll")                                   \
    for (int a_ = 0; a_ < 4; ++a_)                      \
        _Pragma("unroll")                               \
        for (int b_ = 0; b_ < 4; ++b_)                  \
            acc[a_][b_] = (f32x4){0.f, 0.f, 0.f, 0.f};

#define MFMA_STEP(As, Bs)                                                        \
    {                                                                            \
        bf16x8 af_[4], bf_[4];                                                   \
        _Pragma("unroll")                                                        \
        for (int f_ = 0; f_ < 4; ++f_) {                                         \
            af_[f_] = *(const bf16x8*)((As) + (wm*64 + f_*16 + l15)*32 + swz8);  \
            bf_[f_] = *(const bf16x8*)((Bs) + (wn*64 + f_*16 + l15)*32 + swz8);  \
        }                                                                        \
        _Pragma("unroll")                                                        \
        for (int m_ = 0; m_ < 4; ++m_)                                           \
            _Pragma("unroll")                                                    \
            for (int n_ = 0; n_ < 4; ++n_)                                       \
                acc[m_][n_] = __builtin_amdgcn_mfma_f32_16x16x32_bf16(           \
                    af_[m_], bf_[n_], acc[m_][n_], 0, 0, 0);                     \
    }

// Double-buffered K-loop (T3 minimum 2-phase): issue next-tile loads, compute
// current, then one drain+barrier per step.  NIT must be even, >= 4.
#define DBUF_LOOP(ABASE, SA, BBASE, SB, NIT)                                     \
    {                                                                            \
        stage2(ABASE(0), SA, BBASE(0), SB, A0, B0, t);                           \
        SYNCV;                                                                   \
        for (int itp = 0; itp < (NIT)/2 - 1; ++itp) {                            \
            stage2(ABASE(2*itp+1), SA, BBASE(2*itp+1), SB, A1, B1, t);           \
            MFMA_STEP(A0, B0); SYNCV;                                            \
            stage2(ABASE(2*itp+2), SA, BBASE(2*itp+2), SB, A0, B0, t);           \
            MFMA_STEP(A1, B1); SYNCV;                                            \
        }                                                                        \
        stage2(ABASE((NIT)-1), SA, BBASE((NIT)-1), SB, A1, B1, t);               \
        MFMA_STEP(A0, B0); SYNCV;                                                \
        MFMA_STEP(A1, B1);                                                       \
    }

// ---------------------------------------------------------------------------
// x fp32 -> bf16, once. Coalesced: float4 loads / uint2 stores per slot.
// ---------------------------------------------------------------------------
__global__ __launch_bounds__(256) void convert_x(
    const float* __restrict__ x, ushort* __restrict__ xb)
{
    const size_t blk = (size_t)blockIdx.x * 4096;
    #pragma unroll
    for (int c = 0; c < 4; ++c) {
        const size_t s = blk + ((size_t)threadIdx.x + 256 * c) * 4;
        float4 a = *(const float4*)(x + s);
        ushort o[4] = {f2bf(a.x), f2bf(a.y), f2bf(a.z), f2bf(a.w)};
        *(uint2*)(xb + s) = *(uint2*)o;
    }
}

// ---------------------------------------------------------------------------
// Weights -> n-major bf16 (B-operand layout). Tiny one-off.
// ---------------------------------------------------------------------------
__global__ __launch_bounds__(256) void convert_w(
    const float* __restrict__ Wq, const float* __restrict__ Wk,
    const float* __restrict__ Wv, const float* __restrict__ Wo,
    ushort* __restrict__ WTqkv, ushort* __restrict__ WoT)
{
    const int id = blockIdx.x;      // 0..1023
    const int matn = id >> 8;
    const int n = id & 255;
    const int k = threadIdx.x;
    const float* W = (matn == 0) ? Wq : (matn == 1) ? Wk : (matn == 2) ? Wv : Wo;
    ushort v = f2bf(W[(size_t)k * E_ + n]);
    if (matn < 3) WTqkv[((size_t)matn * E_ + n) * E_ + k] = v;
    else          WoT[(size_t)n * E_ + k] = v;
}

// ---------------------------------------------------------------------------
// Fused QKV projection. 12288 blocks, XCD-chunked; nt (0..5) fastest so the 6
// blocks sharing an x panel sit on one XCD. Double-buffered gll staging.
// Epilogue repacks through LDS -> uint4 stores; v transposed in LDS ([e][c]).
// ---------------------------------------------------------------------------
__global__ __launch_bounds__(256) void qkv_mfma(
    const ushort* __restrict__ xb, const ushort* __restrict__ WT,
    const float* __restrict__ bq, const float* __restrict__ bk,
    const float* __restrict__ bv, const float* __restrict__ mask,
    ushort* __restrict__ qb, ushort* __restrict__ kb, ushort* __restrict__ vb)
{
    __shared__ __align__(16) ushort S[128 * RP];   // staging dbuf + repack alias
    BUFS;
    const int id = ((blockIdx.x & 7) * 1536) + (blockIdx.x >> 3);
    const int nt = id % 6;
    const int rc0 = (id / 6) * 128;
    MFMA_PREAMBLE;

    const ushort* Ab = xb + (size_t)rc0 * E_;
    const ushort* Bb = WT + (size_t)nt * 128 * E_;

#define QKA(i) (Ab + (i) * 32)
#define QKB(i) (Bb + (i) * 32)
    DBUF_LOOP(QKA, E_, QKB, E_, 8);
    __syncthreads();

    const int proj = nt >> 1;
    const float* bias = (proj == 0) ? bq : (proj == 1) ? bk : bv;
    float bvv[4];
    #pragma unroll
    for (int fn = 0; fn < 4; ++fn)
        bvv[fn] = bias[(nt * 128 + wn * 64 + fn * 16 + l15) & 255];

    // repack: q/k as [c][e], v as [e][c]
    #pragma unroll
    for (int fm = 0; fm < 4; ++fm)
        #pragma unroll
        for (int fn = 0; fn < 4; ++fn)
            #pragma unroll
            for (int rg = 0; rg < 4; ++rg) {
                const int m = wm * 64 + fm * 16 + lhi * 4 + rg;
                const int n = wn * 64 + fn * 16 + l15;
                const ushort val = f2bf(acc[fm][fn][rg] + bvv[fn]);
                if (proj < 2) S[m * RP + n] = val;
                else          S[n * RP + m] = val;
            }
    __syncthreads();

    const int r = rc0 >> 9, c0 = rc0 & 511;
    if (proj < 2) {
        ushort* dst = (proj == 0) ? qb : kb;
        #pragma unroll
        for (int c = 0; c < 8; ++c) {
            const int idx = t + 256 * c;
            const int mrow = idx >> 4, ne = (idx & 15) * 8;
            uint4 w = *(const uint4*)(S + mrow * RP + ne);
            if (proj == 0) {   // q: * 1/128 * (1-mask)  (exact pow2 scale)
                const float sk = 0.0078125f * (1.0f - mask[rc0 + mrow]);
                ushort* ws = (ushort*)&w;
                #pragma unroll
                for (int jj = 0; jj < 8; ++jj) ws[jj] = f2bf(bf2f(ws[jj]) * sk);
            }
            const int e = (nt & 1) * 128 + ne, h = e >> 5, d = e & 31;
            *(uint4*)(dst + ((((size_t)h * R_ + r) * C_) + c0 + mrow) * D_ + d) = w;
        }
    } else {
        #pragma unroll
        for (int c = 0; c < 8; ++c) {
            const int idx = t + 256 * c;
            const int nrow = idx >> 4, m0 = (idx & 15) * 8;
            uint4 w = *(const uint4*)(S + nrow * RP + m0);
            const int e = (nt & 1) * 128 + nrow, h = e >> 5, d = e & 31;
            *(uint4*)(vb + (((size_t)h * R_ + r) * D_ + d) * C_ + c0 + m0) = w;
        }
    }
}

// ---------------------------------------------------------------------------
// Attention logits. K = R*D split 8-way over r (1024 blocks, one head/XCD).
// ---------------------------------------------------------------------------
__global__ __launch_bounds__(256) void logits_mfma(
    const ushort* __restrict__ qb, const ushort* __restrict__ kb,
    float* __restrict__ partial)
{
    __shared__ __align__(16) ushort S[16384];
    BUFS;
    const int id = ((blockIdx.x & 7) * 128) + (blockIdx.x >> 3);
    const int sub = id & 15;
    const int j0 = (sub & 3) * 128;         // j fastest: 4 blocks share q panel
    const int i0 = (sub >> 2) * 128;
    const int hks = id >> 4;                // 0..63
    const int h = hks >> 3, ks = hks & 7;
    MFMA_PREAMBLE;

    const ushort* Ab = qb + (((size_t)h * R_ + ks * 64) * C_ + i0) * D_;
    const ushort* Bb = kb + (((size_t)h * R_ + ks * 64) * C_ + j0) * D_;

#define LGA(i) (Ab + (size_t)(i) * (C_ * D_))
#define LGB(i) (Bb + (size_t)(i) * (C_ * D_))
    DBUF_LOOP(LGA, D_, LGB, D_, 64);

    float* dst = partial + ((size_t)ks * H_ + h) * C_ * C_;
    #pragma unroll
    for (int fm = 0; fm < 4; ++fm)
        #pragma unroll
        for (int rg = 0; rg < 4; ++rg) {
            const int i = i0 + wm * 64 + fm * 16 + lhi * 4 + rg;
            #pragma unroll
            for (int fn = 0; fn < 4; ++fn) {
                const int j = j0 + wn * 64 + fn * 16 + l15;
                dst[(size_t)i * C_ + j] = acc[fm][fn][rg];
            }
        }
}

// ---------------------------------------------------------------------------
// Sum 8 K-split partials + i-axis mask + softmax over j. fp32 probs out +
// bf16 copy for the context GEMM.
// ---------------------------------------------------------------------------
__global__ __launch_bounds__(256) void softmax_kernel(
    const float* __restrict__ partial, const float* __restrict__ mask,
    float* __restrict__ probs, ushort* __restrict__ Pb)
{
    const int hi = blockIdx.x;
    const int i = hi & 511;
    const int t = threadIdx.x;
    const size_t base = (size_t)hi * C_;
    const size_t stride = (size_t)H_ * C_ * C_;
    float v0 = 0.f, v1 = 0.f;
    #pragma unroll
    for (int ksp = 0; ksp < 8; ++ksp) {
        v0 += partial[ksp * stride + base + t];
        v1 += partial[ksp * stride + base + t + 256];
    }
    const float mi = mask[i];
    const float keep = 1.0f - mi;
    v0 = v0 * keep + mi * (-10000.0f);
    v1 = v1 * keep + mi * (-10000.0f);

    float m = fmaxf(v0, v1);
    #pragma unroll
    for (int off = 32; off > 0; off >>= 1) m = fmaxf(m, __shfl_xor(m, off));
    __shared__ float red[4];
    if ((t & 63) == 0) red[t >> 6] = m;
    __syncthreads();
    m = fmaxf(fmaxf(red[0], red[1]), fmaxf(red[2], red[3]));

    const float e0 = expf(v0 - m), e1 = expf(v1 - m);
    float s = e0 + e1;
    #pragma unroll
    for (int off = 32; off > 0; off >>= 1) s += __shfl_xor(s, off);
    __syncthreads();
    if ((t & 63) == 0) red[t >> 6] = s;
    __syncthreads();
    s = red[0] + red[1] + red[2] + red[3];

    const float inv = 1.0f / s;
    const float p0 = e0 * inv, p1 = e1 * inv;
    probs[base + t] = p0;
    probs[base + t + 256] = p1;
    Pb[base + t] = f2bf(p0);
    Pb[base + t + 256] = f2bf(p1);
}

// ---------------------------------------------------------------------------
// Context: per head, ctx[i, n=(r,d)] = sum_j P[i,j] * vb[h][n][j].
// 4096 blocks XCD-chunked (one head per XCD). LDS-repacked wide stores.
// ---------------------------------------------------------------------------
__global__ __launch_bounds__(256) void context_mfma(
    const ushort* __restrict__ Pb, const ushort* __restrict__ vb,
    ushort* __restrict__ ctxb)
{
    __shared__ __align__(16) ushort S[128 * RP];
    BUFS;
    const int id = ((blockIdx.x & 7) * 512) + (blockIdx.x >> 3);
    const int i0 = (id & 3) * 128;          // i fastest: 4 blocks share vb panel
    const int n0 = ((id >> 2) & 127) * 128;
    const int h = id >> 9;
    MFMA_PREAMBLE;

    const ushort* Ab = Pb + ((size_t)h * C_ + i0) * C_;
    const ushort* Bb = vb + ((size_t)h * R_ * D_ + n0) * C_;

#define CXA(i) (Ab + (i) * 32)
#define CXB(i) (Bb + (i) * 32)
    DBUF_LOOP(CXA, C_, CXB, C_, 16);
    __syncthreads();

    #pragma unroll
    for (int fm = 0; fm < 4; ++fm)
        #pragma unroll
        for (int fn = 0; fn < 4; ++fn)
            #pragma unroll
            for (int rg = 0; rg < 4; ++rg) {
                const int m = wm * 64 + fm * 16 + lhi * 4 + rg;
                const int n = wn * 64 + fn * 16 + l15;
                S[m * RP + n] = f2bf(acc[fm][fn][rg]);
            }
    __syncthreads();

    #pragma unroll
    for (int c = 0; c < 8; ++c) {
        const int idx = t + 256 * c;
        const int mrow = idx >> 4, nl = (idx & 15) * 8;
        uint4 w = *(const uint4*)(S + mrow * RP + nl);
        const int n = n0 + nl;
        const int rr = n >> 5, d = n & 31;
        const size_t rc = (size_t)rr * C_ + i0 + mrow;
        *(uint4*)(ctxb + rc * E_ + h * D_ + d) = w;
    }
}

// ---------------------------------------------------------------------------
// Output projection: out = ctx @ Wo + bo, fp32 out via 2-phase LDS repack.
// ---------------------------------------------------------------------------
__global__ __launch_bounds__(256) void out_proj_mfma(
    const ushort* __restrict__ ctxb, const ushort* __restrict__ WoT,
    const float* __restrict__ bo, float* __restrict__ out)
{
    __shared__ __align__(16) ushort S[128 * RP];
    BUFS;
    float* Sf = (float*)S;                  // 128 x 68 fp32 repack
    const int id = ((blockIdx.x & 7) * 512) + (blockIdx.x >> 3);
    const int n0 = (id & 1) * 128;
    const int rc0 = (id >> 1) * 128;
    MFMA_PREAMBLE;

    const ushort* Ab = ctxb + (size_t)rc0 * E_;
    const ushort* Bb = WoT + (size_t)n0 * E_;

#define OPA(i) (Ab + (i) * 32)
#define OPB(i) (Bb + (i) * 32)
    DBUF_LOOP(OPA, E_, OPB, E_, 8);
    __syncthreads();

    float bvv[4];
    #pragma unroll
    for (int fn = 0; fn < 4; ++fn)
        bvv[fn] = bo[n0 + wn * 64 + fn * 16 + l15];

    #pragma unroll
    for (int p = 0; p < 2; ++p) {
        #pragma unroll
        for (int fm = 0; fm < 4; ++fm)
            #pragma unroll
            for (int fh = 0; fh < 2; ++fh) {
                const int fn = 2 * p + fh;
                #pragma unroll
                for (int rg = 0; rg < 4; ++rg) {
                    const int m = wm * 64 + fm * 16 + lhi * 4 + rg;
                    const int s = wn * 32 + fh * 16 + l15;
                    Sf[m * 68 + s] = acc[fm][fn][rg] + bvv[fn];
                }
            }
        __syncthreads();
        #pragma unroll
        for (int c = 0; c < 8; ++c) {
            const int idx = t + 256 * c;
            const int row = idx >> 4, s0 = (idx & 15) * 4;
            float4 w = *(const float4*)(Sf + row * 68 + s0);
            const int ncol = n0 + (s0 >> 5) * 64 + (2 * p + ((s0 >> 4) & 1)) * 16 + (s0 & 15);
            *(float4*)(out + ((size_t)rc0 + row) * E_ + ncol) = w;
        }
        __syncthreads();
    }
}

// ---------------------------------------------------------------------------
extern "C" void kernel_launch(void* const* d_in, const int* in_sizes, int n_in,
                              void* d_out, int out_size, void* d_ws, size_t ws_size,
                              hipStream_t stream)
{
    const float* x    = (const float*)d_in[0];
    const float* mask = (const float*)d_in[1];
    const float* Wq   = (const float*)d_in[2];
    const float* bq   = (const float*)d_in[3];
    const float* Wk   = (const float*)d_in[4];
    const float* bk   = (const float*)d_in[5];
    const float* Wv   = (const float*)d_in[6];
    const float* bv   = (const float*)d_in[7];
    const float* Wo   = (const float*)d_in[8];
    const float* bo   = (const float*)d_in[9];

    float* out   = (float*)d_out;                       // [R,C,E] fp32
    float* probs = out + (size_t)RC_ * E_;              // [H,C,C] fp32

    char* ws = (char*)d_ws;
    ushort* qb      = (ushort*)(ws);                    // 128 MB  [h][r][c][d]
    ushort* kb      = (ushort*)(ws + 134217728ull);     // 128 MB  [h][r][c][d]
    ushort* vb      = (ushort*)(ws + 268435456ull);     // 128 MB  [h][r][d][c]
    ushort* ctxb    = (ushort*)(ws + 402653184ull);     // 128 MB  [rc][e]
    float*  partial = (float*)(ws + 536870912ull);      // 64 MB   [8][h][i][j]
    ushort* Pb      = (ushort*)(ws + 603979776ull);     // 4 MB    [h][i][j]
    ushort* WTqkv   = (ushort*)(ws + 608174080ull);     // 384 KB
    ushort* WoT     = (ushort*)(ws + 608567296ull);     // 128 KB
    ushort* xb      = (ushort*)(ws + 608700416ull);     // 128 MB  [rc][e]

    convert_x<<<16384, 256, 0, stream>>>(x, xb);
    convert_w<<<1024, 256, 0, stream>>>(Wq, Wk, Wv, Wo, WTqkv, WoT);
    qkv_mfma<<<12288, 256, 0, stream>>>(xb, WTqkv, bq, bk, bv, mask, qb, kb, vb);
    logits_mfma<<<1024, 256, 0, stream>>>(qb, kb, partial);
    softmax_kernel<<<4096, 256, 0, stream>>>(partial, mask, probs, Pb);
    context_mfma<<<4096, 256, 0, stream>>>(Pb, vb, ctxb);
    out_proj_mfma<<<4096, 256, 0, stream>>>(ctxb, WoT, bo, out);
}